// Round 7
// baseline (2281.795 us; speedup 1.0000x reference)
//
#include <hip/hip_runtime.h>
#include <hip/hip_bf16.h>
#include <hip/hip_fp16.h>
#include <math.h>

#define N_NODES 50000
#define N_EDGES 800000
#define N_GRAPHS 128
#define ORIG_FEA 92
#define NBR_FEA 41
#define H 64
#define N_CONV 3
#define BN_EPS 1e-5f
#define KP 48        // padded K per edge row (f16): 41 real + zeros
#define CH 200000    // edges per chunk (4 chunks x 200000 = 800000 exactly)
#define NCHUNK 4
#define TPC 12500    // 16-edge tiles per chunk

typedef _Float16 h8 __attribute__((ext_vector_type(8)));
typedef float f32x4 __attribute__((ext_vector_type(4)));

__device__ __forceinline__ float sigmoidf_(float x) {
    return __fdividef(1.f, 1.f + __expf(-x));
}
__device__ __forceinline__ float softplusf_(float x) {
    return fmaxf(x, 0.f) + __logf(1.f + __expf(-fabsf(x)));
}

// ---------------------------------------------------------------------------
// Fold W_emb2/b_emb2/biases. W2pT[a][j2][k] f16, j2 = gate*64+feat (plane-
// separated), k in [0,64) zero-padded past 41. cfs[a][j2] f32.
// ---------------------------------------------------------------------------
__global__ __launch_bounds__(256) void fold_kernel(
    const float* __restrict__ W_emb2, const float* __restrict__ b_emb2,
    const float* __restrict__ Wf, const float* __restrict__ bf,
    const float* __restrict__ Ws, const float* __restrict__ bs,
    _Float16* __restrict__ W2pT, float* __restrict__ cfs) {
    int a = blockIdx.x >> 1, gate = blockIdx.x & 1;
    const float* W = (gate ? Ws : Wf) + a * 192 * H + 128 * H;  // [64][64]
    const float* bias = (gate ? bs : bf) + a * H;
    _Float16* out = W2pT + a * 128 * 64 + gate * 64 * 64;
    float* cout = cfs + a * 128 + gate * 64;
    for (int idx = threadIdx.x; idx < 64 * 64; idx += blockDim.x) {
        int j = idx >> 6, k = idx & 63;
        float acc = 0.f;
        if (k < NBR_FEA)
            for (int m = 0; m < H; ++m) acc += W_emb2[k * H + m] * W[m * H + j];
        out[j * 64 + k] = (_Float16)acc;
    }
    for (int j = threadIdx.x; j < H; j += blockDim.x) {
        float acc = bias[j];
        for (int m = 0; m < H; ++m) acc += b_emb2[m] * W[m * H + j];
        cout[j] = acc;
    }
}

// ---------------------------------------------------------------------------
// h = x @ W_emb1 + b_emb1  -> state
// ---------------------------------------------------------------------------
__global__ __launch_bounds__(256) void embed_kernel(
    const float* __restrict__ x, const float* __restrict__ W,
    const float* __restrict__ b, float* __restrict__ state) {
    __shared__ float lw[ORIG_FEA * H];
    for (int i = threadIdx.x; i < ORIG_FEA * H; i += blockDim.x) lw[i] = W[i];
    __syncthreads();
    int lane = threadIdx.x & 63;
    int wid = (blockIdx.x * blockDim.x + threadIdx.x) >> 6;
    int nw = (gridDim.x * blockDim.x) >> 6;
    for (int n = wid; n < N_NODES; n += nw) {
        int nu = __builtin_amdgcn_readfirstlane(n);
        const float* xr = x + (size_t)nu * ORIG_FEA;
        float acc = b[lane];
#pragma unroll
        for (int k = 0; k < ORIG_FEA; ++k) acc += xr[k] * lw[k * H + lane];
        state[(size_t)nu * H + lane] = acc;
    }
}

// ---------------------------------------------------------------------------
// CSR construction
// ---------------------------------------------------------------------------
__global__ __launch_bounds__(256) void hist_kernel(
    const int* __restrict__ ei, int* __restrict__ deg) {
    int e = blockIdx.x * blockDim.x + threadIdx.x;
    if (e < N_EDGES) atomicAdd(&deg[ei[N_EDGES + e]], 1);
}

__global__ __launch_bounds__(256) void scan_kernel(
    const int* __restrict__ deg, int* __restrict__ off, int* __restrict__ cur) {
    __shared__ int part[256];
    const int CHN = (N_NODES + 255) / 256;
    int t = threadIdx.x;
    int lo = t * CHN, hi = min(lo + CHN, N_NODES);
    int s = 0;
    for (int i = lo; i < hi; ++i) s += deg[i];
    part[t] = s;
    __syncthreads();
    for (int o = 1; o < 256; o <<= 1) {
        int v = (t >= o) ? part[t - o] : 0;
        __syncthreads();
        part[t] += v;
        __syncthreads();
    }
    int run = (t == 0) ? 0 : part[t - 1];
    for (int i = lo; i < hi; ++i) {
        off[i] = run;
        cur[i] = run;
        run += deg[i];
    }
    if (t == 255) off[N_NODES] = run;
}

__global__ __launch_bounds__(256) void scatter_kernel(
    const int* __restrict__ ei, int* __restrict__ cur, int* __restrict__ pos,
    int* __restrict__ src_s, int* __restrict__ dst_s) {
    int e = blockIdx.x * blockDim.x + threadIdx.x;
    if (e < N_EDGES) {
        int d = ei[N_EDGES + e];
        int p = atomicAdd(&cur[d], 1);
        pos[e] = p;
        src_s[p] = ei[e];
        dst_s[p] = d;
    }
}

// ---------------------------------------------------------------------------
// Pack edge_attr -> f16 rows [KP=48] in CSR slot order. Sequential reads,
// scattered 96B writes (fire-and-forget). Pads (k>=41) zeroed.
// ---------------------------------------------------------------------------
__global__ __launch_bounds__(256) void pack_ea_kernel(
    const int* __restrict__ pos, const float* __restrict__ ea,
    _Float16* __restrict__ ea_p) {
    const int DPR = KP / 2;  // 24 dwords per row
    long long total = (long long)N_EDGES * DPR;
    for (long long t = (long long)blockIdx.x * blockDim.x + threadIdx.x;
         t < total; t += (long long)gridDim.x * blockDim.x) {
        int e = (int)(t / DPR), d = (int)(t % DPR);
        float v0 = (2 * d < NBR_FEA) ? ea[(size_t)e * NBR_FEA + 2 * d] : 0.f;
        float v1 = (2 * d + 1 < NBR_FEA) ? ea[(size_t)e * NBR_FEA + 2 * d + 1] : 0.f;
        union { _Float16 h[2]; unsigned u; } cv;
        cv.h[0] = (_Float16)v0;
        cv.h[1] = (_Float16)v1;
        int p = pos[e];
        *(unsigned*)(ea_p + (size_t)p * KP + 2 * d) = cv.u;
    }
}

// ---------------------------------------------------------------------------
// node_proj_bn: (BN_{a-1}+ReLU if mode) fused with 4 projections, outputs
// plane-separated: NPi[n][feat]=pf, NPi[n][64+feat]=ps; NPj: qf/qs.
// ---------------------------------------------------------------------------
__global__ __launch_bounds__(256) void node_proj_bn_kernel(
    const float* __restrict__ state, const float* __restrict__ stats,
    const float* __restrict__ gamma, const float* __restrict__ beta,
    const float* __restrict__ Wf, const float* __restrict__ Ws,
    float* __restrict__ NPi, float* __restrict__ NPj, int mode) {
    __shared__ float lw[4 * H * H];
    __shared__ float slot[4][H];
    for (int i = threadIdx.x; i < H * H; i += blockDim.x) {
        lw[i] = Wf[i];
        lw[H * H + i] = Wf[H * H + i];
        lw[2 * H * H + i] = Ws[i];
        lw[3 * H * H + i] = Ws[H * H + i];
    }
    int lane = threadIdx.x & 63;
    int wl = threadIdx.x >> 6;
    float A = 1.f, B = 0.f;
    if (mode) {
        const float inv_n = 1.f / (float)N_NODES;
        float mu = stats[lane] * inv_n;
        float var = stats[H + lane] * inv_n - mu * mu;
        float inv = rsqrtf(var + BN_EPS);
        A = inv * gamma[lane];
        B = beta[lane] - mu * A;
    }
    __syncthreads();
    int wid = (blockIdx.x * blockDim.x + threadIdx.x) >> 6;
    int nw = (gridDim.x * blockDim.x) >> 6;
    for (int n = wid; n < N_NODES; n += nw) {
        float z = state[(size_t)n * H + lane];
        float hn = mode ? fmaxf(z * A + B, 0.f) : z;
        slot[wl][lane] = hn;
        float pf = 0.f, qf = 0.f, ps = 0.f, qs = 0.f;
#pragma unroll
        for (int k = 0; k < H; ++k) {
            float s = slot[wl][k];
            pf += s * lw[k * H + lane];
            qf += s * lw[H * H + k * H + lane];
            ps += s * lw[2 * H * H + k * H + lane];
            qs += s * lw[3 * H * H + k * H + lane];
        }
        NPi[(size_t)n * 128 + lane] = pf;
        NPi[(size_t)n * 128 + 64 + lane] = ps;
        NPj[(size_t)n * 128 + lane] = qf;
        NPj[(size_t)n * 128 + 64 + lane] = qs;
    }
}

// ---------------------------------------------------------------------------
// msg_gemm: one wave per 16-edge CSR tile. MFMA the ea@W2 part, add gathered
// NPi[dst]+NPj[src] (plane-separated -> gate pair in same lane), apply
// sigmoid*softplus, write msg[p][64] f16 (tile-contiguous, coalesced).
// A layout (16x16x32): lane holds A[row=lane&15][k=(lane>>4)*8+i]
// B: lane holds B[k=(lane>>4)*8+i][col=lane&15]  (k-contiguous -> from W2pT)
// C: col=lane&15, row=(lane>>4)*4+reg
// ---------------------------------------------------------------------------
__global__ __launch_bounds__(256, 3) void msg_gemm_kernel(
    const _Float16* __restrict__ ea_p, const int* __restrict__ src_s,
    const int* __restrict__ dst_s, const float* __restrict__ NPi,
    const float* __restrict__ NPj, const _Float16* __restrict__ W2pT,
    const float* __restrict__ cfs, _Float16* __restrict__ msgb, int chunk) {
    __shared__ __align__(16) _Float16 lst[4][16 * 64];
    int lane = threadIdx.x & 63;
    int wl = threadIdx.x >> 6;
    int m15 = lane & 15, g = lane >> 4;

    // B fragments (loop-invariant; 16 x dwordx4 = 64 VGPR)
    h8 bfr[8][2];
#pragma unroll
    for (int nt = 0; nt < 8; ++nt)
#pragma unroll
        for (int ks = 0; ks < 2; ++ks) {
            int j2 = nt * 16 + m15;
            union { uint4 u; h8 h; } cv;
            cv.u = *(const uint4*)(W2pT + (size_t)j2 * 64 + ks * 32 + g * 8);
            bfr[nt][ks] = cv.h;
        }
    float cf_[4], cs_[4];
#pragma unroll
    for (int nt = 0; nt < 4; ++nt) {
        cf_[nt] = cfs[nt * 16 + m15];
        cs_[nt] = cfs[64 + nt * 16 + m15];
    }

    int local = blockIdx.x * 4 + wl;         // tile within chunk [0,12500)
    int base = chunk * CH + local * 16;      // global CSR position of row 0

    // A fragments: direct global loads (rows 96B, 16B-aligned)
    const _Float16* rowp = ea_p + (size_t)(base + m15) * KP;
    h8 afr[2];
    {
        union { uint4 u; h8 h; } cv0, cv1;
        cv0.u = *(const uint4*)(rowp + g * 8);           // k = g*8..g*8+7
        afr[0] = cv0.h;
        // ks=1: k = 32+g*8..+7; rows only hold k<48 -> lanes g>=2 are zero
        const _Float16* p1 = rowp + ((g < 2) ? (32 + g * 8) : 0);
        uint4 r1 = *(const uint4*)p1;
        if (g >= 2) { r1.x = 0u; r1.y = 0u; r1.z = 0u; r1.w = 0u; }
        cv1.u = r1;
        afr[1] = cv1.h;
    }

    f32x4 c[8];
#pragma unroll
    for (int nt = 0; nt < 8; ++nt) c[nt] = (f32x4)(0.f);
#pragma unroll
    for (int ks = 0; ks < 2; ++ks)
#pragma unroll
        for (int nt = 0; nt < 8; ++nt)
            c[nt] = __builtin_amdgcn_mfma_f32_16x16x32_f16(afr[ks], bfr[nt][ks],
                                                           c[nt], 0, 0, 0);
    // epilogue: + NP terms, gates, stage msg to LDS in [row][feat] layout
#pragma unroll
    for (int r = 0; r < 4; ++r) {
        int prow = base + 4 * g + r;
        int dv = dst_s[prow];
        int sv = src_s[prow];
        const float* npid = NPi + (size_t)dv * 128;
        const float* npjs = NPj + (size_t)sv * 128;
#pragma unroll
        for (int nt = 0; nt < 4; ++nt) {
            int feat = nt * 16 + m15;
            float af = c[nt][r] + cf_[nt] + npid[feat] + npjs[feat];
            float as = c[nt + 4][r] + cs_[nt] + npid[64 + feat] + npjs[64 + feat];
            float m = sigmoidf_(af) * softplusf_(as);
            lst[wl][(4 * g + r) * 64 + feat] = (_Float16)m;
        }
    }
    // wave-local LDS (compiler inserts lgkmcnt waits); coalesced 2KB store
    const uint4* lr = (const uint4*)&lst[wl][0];
    uint4 o0 = lr[lane * 2];
    uint4 o1 = lr[lane * 2 + 1];
    uint4* gp = (uint4*)(msgb + (size_t)local * 1024);
    gp[lane * 2] = o0;
    gp[lane * 2 + 1] = o1;
}

// ---------------------------------------------------------------------------
// agg: wave per node (owned by the chunk containing its first edge).
// acc = residual(BN if mode) + sum of msg rows (1 ushort load/lane/edge,
// sequential 128B rows). Writes state, accumulates BN stats.
// ---------------------------------------------------------------------------
__global__ __launch_bounds__(256) void agg_kernel(
    const int* __restrict__ off, const _Float16* __restrict__ msg,
    const float* __restrict__ stats_prev, const float* __restrict__ gamma,
    const float* __restrict__ beta, float* __restrict__ state,
    float* __restrict__ stats_out, int mode, int chunk) {
    int lane = threadIdx.x & 63;
    float A = 1.f, B = 0.f;
    if (mode) {
        const float inv_n = 1.f / (float)N_NODES;
        float mu = stats_prev[lane] * inv_n;
        float var = stats_prev[H + lane] * inv_n - mu * mu;
        float inv = rsqrtf(var + BN_EPS);
        A = inv * gamma[lane];
        B = beta[lane] - mu * A;
    }
    int lo = chunk * CH;
    const _Float16* b0 = msg + (size_t)(chunk & 1) * CH * 64;
    const _Float16* b1 = msg + (size_t)((chunk + 1) & 1) * CH * 64;
    float s = 0.f, s2 = 0.f;
    int wid = (blockIdx.x * blockDim.x + threadIdx.x) >> 6;
    int nw = (gridDim.x * blockDim.x) >> 6;
    for (int n = wid; n < N_NODES; n += nw) {
        int nu = __builtin_amdgcn_readfirstlane(n);
        int e0 = __builtin_amdgcn_readfirstlane(off[nu]);
        int cn = e0 / CH;
        if (cn > NCHUNK - 1) cn = NCHUNK - 1;
        if (cn != chunk) continue;
        int e1 = __builtin_amdgcn_readfirstlane(off[nu + 1]);
        float z = state[(size_t)nu * H + lane];
        float acc = mode ? fmaxf(z * A + B, 0.f) : z;
#pragma unroll 4
        for (int p = e0; p < e1; ++p) {
            const _Float16* src = (p < lo + CH)
                                      ? (b0 + (size_t)(p - lo) * 64)
                                      : (b1 + (size_t)(p - lo - CH) * 64);
            acc += (float)src[lane];
        }
        state[(size_t)nu * H + lane] = acc;
        s += acc;
        s2 += acc * acc;
    }
    atomicAdd(&stats_out[lane], s);
    atomicAdd(&stats_out[H + lane], s2);
}

// ---------------------------------------------------------------------------
// Pool with fused final BN, then MLP head
// ---------------------------------------------------------------------------
__global__ __launch_bounds__(256) void pool_bn_kernel(
    const float* __restrict__ state, const float* __restrict__ stats,
    const float* __restrict__ gamma, const float* __restrict__ beta,
    const int* __restrict__ batch, float* __restrict__ gsum,
    float* __restrict__ gcnt) {
    int lane = threadIdx.x & 63;
    const float inv_n = 1.f / (float)N_NODES;
    float mu = stats[lane] * inv_n;
    float var = stats[H + lane] * inv_n - mu * mu;
    float inv = rsqrtf(var + BN_EPS);
    float A = inv * gamma[lane];
    float B = beta[lane] - mu * A;
    int wid = (blockIdx.x * blockDim.x + threadIdx.x) >> 6;
    int nw = (gridDim.x * blockDim.x) >> 6;
    for (int n = wid; n < N_NODES; n += nw) {
        int nu = __builtin_amdgcn_readfirstlane(n);
        int g = batch[nu];
        float v = state[(size_t)nu * H + lane] * A + B;
        atomicAdd(&gsum[(size_t)g * H + lane], v);
        if (lane == 0) atomicAdd(&gcnt[g], 1.f);
    }
}

__global__ __launch_bounds__(64) void mlp_kernel(
    const float* __restrict__ gsum, const float* __restrict__ gcnt,
    const float* __restrict__ W1, const float* __restrict__ b1,
    const float* __restrict__ W2, const float* __restrict__ b2,
    const float* __restrict__ Wo, const float* __restrict__ bo,
    float* __restrict__ out) {
    int g = blockIdx.x;
    int lane = threadIdx.x;
    __shared__ float y[H];
    float cnt = fmaxf(gcnt[g], 1.f);
    y[lane] = gsum[(size_t)g * H + lane] / cnt;
    __syncthreads();
    float acc = b1[lane];
#pragma unroll
    for (int k = 0; k < H; ++k) acc += y[k] * W1[k * H + lane];
    float y1 = softplusf_(acc);
    __syncthreads();
    y[lane] = y1;
    __syncthreads();
    acc = b2[lane];
#pragma unroll
    for (int k = 0; k < H; ++k) acc += y[k] * W2[k * H + lane];
    float y2 = softplusf_(acc);
    float t = y2 * Wo[lane];
#pragma unroll
    for (int o = 32; o > 0; o >>= 1) t += __shfl_down(t, o, 64);
    if (lane == 0) out[g] = t + bo[0];
}

extern "C" void kernel_launch(void* const* d_in, const int* in_sizes, int n_in,
                              void* d_out, int out_size, void* d_ws, size_t ws_size,
                              hipStream_t stream) {
    const float* x = (const float*)d_in[0];
    const float* ea = (const float*)d_in[1];
    const int* ei = (const int*)d_in[2];
    const int* batch = (const int*)d_in[3];
    const float* W_emb1 = (const float*)d_in[4];
    const float* b_emb1 = (const float*)d_in[5];
    const float* W_emb2 = (const float*)d_in[6];
    const float* b_emb2 = (const float*)d_in[7];
    const float* Wf = (const float*)d_in[8];
    const float* bf = (const float*)d_in[9];
    const float* Ws = (const float*)d_in[10];
    const float* bs = (const float*)d_in[11];
    const float* gamma = (const float*)d_in[12];
    const float* beta = (const float*)d_in[13];
    const float* W1 = (const float*)d_in[14];
    const float* b1 = (const float*)d_in[15];
    const float* W2 = (const float*)d_in[16];
    const float* b2 = (const float*)d_in[17];
    const float* Wo = (const float*)d_in[18];
    const float* bo = (const float*)d_in[19];
    float* out = (float*)d_out;

    float* w = (float*)d_ws;
    // ---- zeroed region (58704 floats = 234816 B, 16B-aligned end) ----
    float* stats = w;                          // 384
    float* gsum = stats + 3 * 2 * H;           // 8192
    float* gcnt = gsum + N_GRAPHS * H;         // 128
    int* deg = (int*)(gcnt + N_GRAPHS);        // 50000
    const size_t zero_elems = 3 * 2 * H + N_GRAPHS * H + N_GRAPHS + N_NODES;
    // ---- scratch ----
    _Float16* ea_p = (_Float16*)(w + zero_elems);        // 800000*48 f16 = 76.8 MB
    _Float16* msg = ea_p + (size_t)N_EDGES * KP;         // 2*CH*64 f16 = 51.2 MB
    int* cur = (int*)msg;                                // alias (used pre-gemm)
    int* pos = cur + N_NODES;                            // alias (used pre-gemm)
    int* off = (int*)(msg + (size_t)2 * CH * 64);        // 50004 (padded)
    int* src_s = off + 50004;                            // 800000
    int* dst_s = src_s + N_EDGES;                        // 800000
    _Float16* W2pT = (_Float16*)(dst_s + N_EDGES);       // 3*128*64 f16
    float* cfs = (float*)(W2pT + 3 * 128 * 64);          // 3*128
    float* state = cfs + 3 * 128;                        // 3.2M
    float* NPi = state + (size_t)N_NODES * H;            // 6.4M
    float* NPj = NPi + (size_t)N_NODES * 128;            // 6.4M
    // total ~198.9 MB (< 202.3 MB proven available in round 4/5)

    hipMemsetAsync(w, 0, zero_elems * sizeof(float), stream);

    fold_kernel<<<6, 256, 0, stream>>>(W_emb2, b_emb2, Wf, bf, Ws, bs, W2pT, cfs);
    embed_kernel<<<512, 256, 0, stream>>>(x, W_emb1, b_emb1, state);
    hist_kernel<<<(N_EDGES + 255) / 256, 256, 0, stream>>>(ei, deg);
    scan_kernel<<<1, 256, 0, stream>>>(deg, off, cur);
    scatter_kernel<<<(N_EDGES + 255) / 256, 256, 0, stream>>>(ei, cur, pos, src_s, dst_s);
    pack_ea_kernel<<<4096, 256, 0, stream>>>(pos, ea, ea_p);

    for (int a = 0; a < N_CONV; ++a) {
        const float* sp = a > 0 ? stats + (a - 1) * 2 * H : stats;
        const float* gp = a > 0 ? gamma + (a - 1) * H : gamma;
        const float* bp = a > 0 ? beta + (a - 1) * H : beta;
        int mode = a > 0 ? 1 : 0;
        node_proj_bn_kernel<<<512, 256, 0, stream>>>(
            state, sp, gp, bp, Wf + a * 192 * H, Ws + a * 192 * H, NPi, NPj, mode);
        const _Float16* Wl = W2pT + a * 128 * 64;
        const float* cl = cfs + a * 128;
        float* so = stats + a * 2 * H;
        // interleaved chunk schedule: g0 g1 a0 g2 a1 g3 a2 a3 (2 msg buffers)
        msg_gemm_kernel<<<TPC / 4, 256, 0, stream>>>(
            ea_p, src_s, dst_s, NPi, NPj, Wl, cl, msg + (size_t)(0 & 1) * CH * 64, 0);
        msg_gemm_kernel<<<TPC / 4, 256, 0, stream>>>(
            ea_p, src_s, dst_s, NPi, NPj, Wl, cl, msg + (size_t)(1 & 1) * CH * 64, 1);
        agg_kernel<<<784, 256, 0, stream>>>(off, msg, sp, gp, bp, state, so, mode, 0);
        msg_gemm_kernel<<<TPC / 4, 256, 0, stream>>>(
            ea_p, src_s, dst_s, NPi, NPj, Wl, cl, msg + (size_t)(2 & 1) * CH * 64, 2);
        agg_kernel<<<784, 256, 0, stream>>>(off, msg, sp, gp, bp, state, so, mode, 1);
        msg_gemm_kernel<<<TPC / 4, 256, 0, stream>>>(
            ea_p, src_s, dst_s, NPi, NPj, Wl, cl, msg + (size_t)(3 & 1) * CH * 64, 3);
        agg_kernel<<<784, 256, 0, stream>>>(off, msg, sp, gp, bp, state, so, mode, 2);
        agg_kernel<<<784, 256, 0, stream>>>(off, msg, sp, gp, bp, state, so, mode, 3);
    }

    pool_bn_kernel<<<784, 256, 0, stream>>>(state, stats + 2 * 2 * H,
                                            gamma + 2 * H, beta + 2 * H,
                                            batch, gsum, gcnt);
    mlp_kernel<<<128, 64, 0, stream>>>(gsum, gcnt, W1, b1, W2, b2, Wo, bo, out);
}

// Round 8
// 1575.058 us; speedup vs baseline: 1.4487x; 1.4487x over previous
//
#include <hip/hip_runtime.h>
#include <hip/hip_bf16.h>
#include <hip/hip_fp16.h>
#include <math.h>

#define N_NODES 50000
#define N_EDGES 800000
#define N_GRAPHS 128
#define ORIG_FEA 92
#define NBR_FEA 41
#define H 64
#define N_CONV 3
#define BN_EPS 1e-5f
#define KP 48        // padded K per edge row (f16): 41 real + zeros

typedef _Float16 h8 __attribute__((ext_vector_type(8)));
typedef float f32x4 __attribute__((ext_vector_type(4)));

__device__ __forceinline__ float sigmoidf_(float x) {
    return __fdividef(1.f, 1.f + __expf(-x));
}
__device__ __forceinline__ float softplusf_(float x) {
    return fmaxf(x, 0.f) + __logf(1.f + __expf(-fabsf(x)));
}

// ---------------------------------------------------------------------------
// Fold W_emb2/b_emb2/biases. W2pT[a][j2][k] f16, j2 = gate*64+feat (plane-
// separated), k in [0,64) zero-padded past 41. cfs[a][j2] f32.
// ---------------------------------------------------------------------------
__global__ __launch_bounds__(256) void fold_kernel(
    const float* __restrict__ W_emb2, const float* __restrict__ b_emb2,
    const float* __restrict__ Wf, const float* __restrict__ bf,
    const float* __restrict__ Ws, const float* __restrict__ bs,
    _Float16* __restrict__ W2pT, float* __restrict__ cfs) {
    int a = blockIdx.x >> 1, gate = blockIdx.x & 1;
    const float* W = (gate ? Ws : Wf) + a * 192 * H + 128 * H;  // [64][64]
    const float* bias = (gate ? bs : bf) + a * H;
    _Float16* out = W2pT + a * 128 * 64 + gate * 64 * 64;
    float* cout = cfs + a * 128 + gate * 64;
    for (int idx = threadIdx.x; idx < 64 * 64; idx += blockDim.x) {
        int j = idx >> 6, k = idx & 63;
        float acc = 0.f;
        if (k < NBR_FEA)
            for (int m = 0; m < H; ++m) acc += W_emb2[k * H + m] * W[m * H + j];
        out[j * 64 + k] = (_Float16)acc;
    }
    for (int j = threadIdx.x; j < H; j += blockDim.x) {
        float acc = bias[j];
        for (int m = 0; m < H; ++m) acc += b_emb2[m] * W[m * H + j];
        cout[j] = acc;
    }
}

// ---------------------------------------------------------------------------
// h = x @ W_emb1 + b_emb1  -> state
// ---------------------------------------------------------------------------
__global__ __launch_bounds__(256) void embed_kernel(
    const float* __restrict__ x, const float* __restrict__ W,
    const float* __restrict__ b, float* __restrict__ state) {
    __shared__ float lw[ORIG_FEA * H];
    for (int i = threadIdx.x; i < ORIG_FEA * H; i += blockDim.x) lw[i] = W[i];
    __syncthreads();
    int lane = threadIdx.x & 63;
    int wid = (blockIdx.x * blockDim.x + threadIdx.x) >> 6;
    int nw = (gridDim.x * blockDim.x) >> 6;
    for (int n = wid; n < N_NODES; n += nw) {
        int nu = __builtin_amdgcn_readfirstlane(n);
        const float* xr = x + (size_t)nu * ORIG_FEA;
        float acc = b[lane];
#pragma unroll
        for (int k = 0; k < ORIG_FEA; ++k) acc += xr[k] * lw[k * H + lane];
        state[(size_t)nu * H + lane] = acc;
    }
}

// ---------------------------------------------------------------------------
// CSR construction
// ---------------------------------------------------------------------------
__global__ __launch_bounds__(256) void hist_kernel(
    const int* __restrict__ ei, int* __restrict__ deg) {
    int e = blockIdx.x * blockDim.x + threadIdx.x;
    if (e < N_EDGES) atomicAdd(&deg[ei[N_EDGES + e]], 1);
}

__global__ __launch_bounds__(256) void scan_kernel(
    const int* __restrict__ deg, int* __restrict__ off, int* __restrict__ cur) {
    __shared__ int part[256];
    const int CHN = (N_NODES + 255) / 256;
    int t = threadIdx.x;
    int lo = t * CHN, hi = min(lo + CHN, N_NODES);
    int s = 0;
    for (int i = lo; i < hi; ++i) s += deg[i];
    part[t] = s;
    __syncthreads();
    for (int o = 1; o < 256; o <<= 1) {
        int v = (t >= o) ? part[t - o] : 0;
        __syncthreads();
        part[t] += v;
        __syncthreads();
    }
    int run = (t == 0) ? 0 : part[t - 1];
    for (int i = lo; i < hi; ++i) {
        off[i] = run;
        cur[i] = run;
        run += deg[i];
    }
    if (t == 255) off[N_NODES] = run;
}

__global__ __launch_bounds__(256) void scatter_kernel(
    const int* __restrict__ ei, int* __restrict__ cur, int* __restrict__ pos,
    int* __restrict__ src_s) {
    int e = blockIdx.x * blockDim.x + threadIdx.x;
    if (e < N_EDGES) {
        int d = ei[N_EDGES + e];
        int p = atomicAdd(&cur[d], 1);
        pos[e] = p;
        src_s[p] = ei[e];
    }
}

// ---------------------------------------------------------------------------
// Pack edge_attr -> f16 rows [KP=48] in CSR slot order. Sequential reads,
// scattered 96B writes (fire-and-forget). Pads (k>=41) zeroed.
// ---------------------------------------------------------------------------
__global__ __launch_bounds__(256) void pack_ea_kernel(
    const int* __restrict__ pos, const float* __restrict__ ea,
    _Float16* __restrict__ ea_p) {
    const int DPR = KP / 2;  // 24 dwords per row
    long long total = (long long)N_EDGES * DPR;
    for (long long t = (long long)blockIdx.x * blockDim.x + threadIdx.x;
         t < total; t += (long long)gridDim.x * blockDim.x) {
        int e = (int)(t / DPR), d = (int)(t % DPR);
        float v0 = (2 * d < NBR_FEA) ? ea[(size_t)e * NBR_FEA + 2 * d] : 0.f;
        float v1 = (2 * d + 1 < NBR_FEA) ? ea[(size_t)e * NBR_FEA + 2 * d + 1] : 0.f;
        union { _Float16 h[2]; unsigned u; } cv;
        cv.h[0] = (_Float16)v0;
        cv.h[1] = (_Float16)v1;
        int p = pos[e];
        *(unsigned*)(ea_p + (size_t)p * KP + 2 * d) = cv.u;
    }
}

// ---------------------------------------------------------------------------
// node_proj_bn: (BN_{a-1}+ReLU if mode) fused with 4 projections, outputs
// plane-separated: NPi[n][feat]=pf, NPi[n][64+feat]=ps; NPj: qf/qs.
// ---------------------------------------------------------------------------
__global__ __launch_bounds__(256) void node_proj_bn_kernel(
    const float* __restrict__ state, const float* __restrict__ stats,
    const float* __restrict__ gamma, const float* __restrict__ beta,
    const float* __restrict__ Wf, const float* __restrict__ Ws,
    float* __restrict__ NPi, float* __restrict__ NPj, int mode) {
    __shared__ float lw[4 * H * H];
    __shared__ float slot[4][H];
    for (int i = threadIdx.x; i < H * H; i += blockDim.x) {
        lw[i] = Wf[i];
        lw[H * H + i] = Wf[H * H + i];
        lw[2 * H * H + i] = Ws[i];
        lw[3 * H * H + i] = Ws[H * H + i];
    }
    int lane = threadIdx.x & 63;
    int wl = threadIdx.x >> 6;
    float A = 1.f, B = 0.f;
    if (mode) {
        const float inv_n = 1.f / (float)N_NODES;
        float mu = stats[lane] * inv_n;
        float var = stats[H + lane] * inv_n - mu * mu;
        float inv = rsqrtf(var + BN_EPS);
        A = inv * gamma[lane];
        B = beta[lane] - mu * A;
    }
    __syncthreads();
    int wid = (blockIdx.x * blockDim.x + threadIdx.x) >> 6;
    int nw = (gridDim.x * blockDim.x) >> 6;
    for (int n = wid; n < N_NODES; n += nw) {
        float z = state[(size_t)n * H + lane];
        float hn = mode ? fmaxf(z * A + B, 0.f) : z;
        slot[wl][lane] = hn;
        float pf = 0.f, qf = 0.f, ps = 0.f, qs = 0.f;
#pragma unroll
        for (int k = 0; k < H; ++k) {
            float s = slot[wl][k];
            pf += s * lw[k * H + lane];
            qf += s * lw[H * H + k * H + lane];
            ps += s * lw[2 * H * H + k * H + lane];
            qs += s * lw[3 * H * H + k * H + lane];
        }
        NPi[(size_t)n * 128 + lane] = pf;
        NPi[(size_t)n * 128 + 64 + lane] = ps;
        NPj[(size_t)n * 128 + lane] = qf;
        NPj[(size_t)n * 128 + 64 + lane] = qs;
    }
}

// ---------------------------------------------------------------------------
// Fused edge kernel: wave per node, CSR bucket in 16-edge MFMA tiles.
//   A[row=lane&15][k=(lane>>4)*8+i] from ea_p (sequential);
//   B[k][col] resident in VGPRs (staged via LDS);
//   C: col=lane&15, row=(lane>>4)*4+reg.
// Epilogue per tile: af/as = C + cfs + NPi(node, in regs) + NPj[src](gather),
// msg = sigmoid*softplus elementwise in C-space, column-sum over 16 rows via
// per-lane 4-row sum + shfl_xor(16,32) butterfly, accumulate into node acc.
// No msg materialization, no atomics, BN stats fused.
// ---------------------------------------------------------------------------
__global__ __launch_bounds__(256, 3) void edge_mfma_kernel(
    const int* __restrict__ off, const int* __restrict__ src_s,
    const _Float16* __restrict__ ea_p,
    const float* __restrict__ NPi, const float* __restrict__ NPj,
    const _Float16* __restrict__ W2pT, const float* __restrict__ cfs,
    const float* __restrict__ stats_prev, const float* __restrict__ gamma,
    const float* __restrict__ beta, float* __restrict__ state,
    float* __restrict__ stats_out, int mode) {
    __shared__ __align__(16) _Float16 lB[128 * 64];  // 16 KB staged weights
    for (int i = threadIdx.x * 8; i < 128 * 64; i += blockDim.x * 8)
        *(uint4*)(lB + i) = *(const uint4*)(W2pT + i);
    __syncthreads();
    int lane = threadIdx.x & 63;
    int m15 = lane & 15, g = lane >> 4;
    // B fragments (64 VGPR); remat worst-case is a cheap ds_read
    h8 bfr[8][2];
#pragma unroll
    for (int nt = 0; nt < 8; ++nt)
#pragma unroll
        for (int ks = 0; ks < 2; ++ks) {
            union { uint4 u; h8 h; } cv;
            cv.u = *(const uint4*)(lB + (nt * 16 + m15) * 64 + ks * 32 + g * 8);
            bfr[nt][ks] = cv.h;
        }
    float cfl[4], csl[4];
#pragma unroll
    for (int nt = 0; nt < 4; ++nt) {
        cfl[nt] = cfs[nt * 16 + m15];
        csl[nt] = cfs[64 + nt * 16 + m15];
    }
    float A = 1.f, B = 0.f;
    if (mode) {
        const float inv_n = 1.f / (float)N_NODES;
        float mu = stats_prev[lane] * inv_n;
        float var = stats_prev[H + lane] * inv_n - mu * mu;
        float inv = rsqrtf(var + BN_EPS);
        A = inv * gamma[lane];
        B = beta[lane] - mu * A;
    }
    float s = 0.f, s2 = 0.f;
    int wid = (blockIdx.x * blockDim.x + threadIdx.x) >> 6;
    int nw = (gridDim.x * blockDim.x) >> 6;
    for (int n = wid; n < N_NODES; n += nw) {
        int nu = __builtin_amdgcn_readfirstlane(n);
        float z = state[(size_t)nu * H + lane];
        float acc = mode ? fmaxf(z * A + B, 0.f) : z;  // residual h
        const float* npid = NPi + (size_t)nu * 128;
        float bfv[4], bsv[4];
#pragma unroll
        for (int nt = 0; nt < 4; ++nt) {
            bfv[nt] = cfl[nt] + npid[nt * 16 + m15];
            bsv[nt] = csl[nt] + npid[64 + nt * 16 + m15];
        }
        int e0 = __builtin_amdgcn_readfirstlane(off[nu]);
        int e1 = __builtin_amdgcn_readfirstlane(off[nu + 1]);
        for (int e = e0; e < e1; e += 16) {
            int cnt = e1 - e;
            // A fragments (rows clamped; padded rows masked in epilogue)
            int arow = e + (m15 < cnt ? m15 : 0);
            const _Float16* rowp = ea_p + (size_t)arow * KP;
            h8 afr[2];
            {
                union { uint4 u; h8 h; } cv0, cv1;
                cv0.u = *(const uint4*)(rowp + g * 8);  // k = g*8..+7
                afr[0] = cv0.h;
                const _Float16* p1 = rowp + ((g < 2) ? (32 + g * 8) : 0);
                uint4 r1 = *(const uint4*)p1;
                if (g >= 2) { r1.x = 0u; r1.y = 0u; r1.z = 0u; r1.w = 0u; }
                cv1.u = r1;
                afr[1] = cv1.h;
            }
            f32x4 c[8];
#pragma unroll
            for (int nt = 0; nt < 8; ++nt) c[nt] = (f32x4)(0.f);
#pragma unroll
            for (int ks = 0; ks < 2; ++ks)
#pragma unroll
                for (int nt = 0; nt < 8; ++nt)
                    c[nt] = __builtin_amdgcn_mfma_f32_16x16x32_f16(
                        afr[ks], bfr[nt][ks], c[nt], 0, 0, 0);
            // epilogue: gate elementwise, partial column sums over lane's 4 rows
            float ts0 = 0.f, ts1 = 0.f, ts2 = 0.f, ts3 = 0.f;
#pragma unroll
            for (int r = 0; r < 4; ++r) {
                int rr = 4 * g + r;
                int ee = e + (rr < cnt ? rr : 0);
                int sv = src_s[ee];
                const float* npjs = NPj + (size_t)sv * 128;
                float mul = (rr < cnt) ? 1.f : 0.f;
                {
                    float af = c[0][r] + bfv[0] + npjs[m15];
                    float as = c[4][r] + bsv[0] + npjs[64 + m15];
                    ts0 += mul * sigmoidf_(af) * softplusf_(as);
                }
                {
                    float af = c[1][r] + bfv[1] + npjs[16 + m15];
                    float as = c[5][r] + bsv[1] + npjs[64 + 16 + m15];
                    ts1 += mul * sigmoidf_(af) * softplusf_(as);
                }
                {
                    float af = c[2][r] + bfv[2] + npjs[32 + m15];
                    float as = c[6][r] + bsv[2] + npjs[64 + 32 + m15];
                    ts2 += mul * sigmoidf_(af) * softplusf_(as);
                }
                {
                    float af = c[3][r] + bfv[3] + npjs[48 + m15];
                    float as = c[7][r] + bsv[3] + npjs[64 + 48 + m15];
                    ts3 += mul * sigmoidf_(af) * softplusf_(as);
                }
            }
            // butterfly across the 4 g-groups (lanes ^16, ^32)
            ts0 += __shfl_xor(ts0, 16, 64); ts0 += __shfl_xor(ts0, 32, 64);
            ts1 += __shfl_xor(ts1, 16, 64); ts1 += __shfl_xor(ts1, 32, 64);
            ts2 += __shfl_xor(ts2, 16, 64); ts2 += __shfl_xor(ts2, 32, 64);
            ts3 += __shfl_xor(ts3, 16, 64); ts3 += __shfl_xor(ts3, 32, 64);
            // lane's state feat = lane = g*16+m15 -> select by g
            float v = (g & 2) ? ((g & 1) ? ts3 : ts2) : ((g & 1) ? ts1 : ts0);
            acc += v;
        }
        state[(size_t)nu * H + lane] = acc;
        s += acc;
        s2 += acc * acc;
    }
    atomicAdd(&stats_out[lane], s);
    atomicAdd(&stats_out[H + lane], s2);
}

// ---------------------------------------------------------------------------
// Pool with fused final BN. batch is SORTED: each wave owns a contiguous node
// range, accumulates locally, flushes one atomic row per graph transition.
// ---------------------------------------------------------------------------
__global__ __launch_bounds__(256) void pool_bn_kernel(
    const float* __restrict__ state, const float* __restrict__ stats,
    const float* __restrict__ gamma, const float* __restrict__ beta,
    const int* __restrict__ batch, float* __restrict__ gsum,
    float* __restrict__ gcnt) {
    int lane = threadIdx.x & 63;
    const float inv_n = 1.f / (float)N_NODES;
    float mu = stats[lane] * inv_n;
    float var = stats[H + lane] * inv_n - mu * mu;
    float inv = rsqrtf(var + BN_EPS);
    float A = inv * gamma[lane];
    float B = beta[lane] - mu * A;
    int wid = (blockIdx.x * blockDim.x + threadIdx.x) >> 6;
    int nw = (gridDim.x * blockDim.x) >> 6;
    int per = (N_NODES + nw - 1) / nw;
    int lo = wid * per, hi = min(lo + per, N_NODES);
    if (lo >= hi) return;
    int gcur = __builtin_amdgcn_readfirstlane(batch[lo]);
    float accv = 0.f, cntv = 0.f;
    for (int n = lo; n < hi; ++n) {
        int gn = __builtin_amdgcn_readfirstlane(batch[n]);
        if (gn != gcur) {
            atomicAdd(&gsum[(size_t)gcur * H + lane], accv);
            if (lane == 0) atomicAdd(&gcnt[gcur], cntv);
            gcur = gn;
            accv = 0.f;
            cntv = 0.f;
        }
        accv += state[(size_t)n * H + lane] * A + B;
        cntv += 1.f;
    }
    atomicAdd(&gsum[(size_t)gcur * H + lane], accv);
    if (lane == 0) atomicAdd(&gcnt[gcur], cntv);
}

__global__ __launch_bounds__(64) void mlp_kernel(
    const float* __restrict__ gsum, const float* __restrict__ gcnt,
    const float* __restrict__ W1, const float* __restrict__ b1,
    const float* __restrict__ W2, const float* __restrict__ b2,
    const float* __restrict__ Wo, const float* __restrict__ bo,
    float* __restrict__ out) {
    int g = blockIdx.x;
    int lane = threadIdx.x;
    __shared__ float y[H];
    float cnt = fmaxf(gcnt[g], 1.f);
    y[lane] = gsum[(size_t)g * H + lane] / cnt;
    __syncthreads();
    float acc = b1[lane];
#pragma unroll
    for (int k = 0; k < H; ++k) acc += y[k] * W1[k * H + lane];
    float y1 = softplusf_(acc);
    __syncthreads();
    y[lane] = y1;
    __syncthreads();
    acc = b2[lane];
#pragma unroll
    for (int k = 0; k < H; ++k) acc += y[k] * W2[k * H + lane];
    float y2 = softplusf_(acc);
    float t = y2 * Wo[lane];
#pragma unroll
    for (int o = 32; o > 0; o >>= 1) t += __shfl_down(t, o, 64);
    if (lane == 0) out[g] = t + bo[0];
}

extern "C" void kernel_launch(void* const* d_in, const int* in_sizes, int n_in,
                              void* d_out, int out_size, void* d_ws, size_t ws_size,
                              hipStream_t stream) {
    const float* x = (const float*)d_in[0];
    const float* ea = (const float*)d_in[1];
    const int* ei = (const int*)d_in[2];
    const int* batch = (const int*)d_in[3];
    const float* W_emb1 = (const float*)d_in[4];
    const float* b_emb1 = (const float*)d_in[5];
    const float* W_emb2 = (const float*)d_in[6];
    const float* b_emb2 = (const float*)d_in[7];
    const float* Wf = (const float*)d_in[8];
    const float* bf = (const float*)d_in[9];
    const float* Ws = (const float*)d_in[10];
    const float* bs = (const float*)d_in[11];
    const float* gamma = (const float*)d_in[12];
    const float* beta = (const float*)d_in[13];
    const float* W1 = (const float*)d_in[14];
    const float* b1 = (const float*)d_in[15];
    const float* W2 = (const float*)d_in[16];
    const float* b2 = (const float*)d_in[17];
    const float* Wo = (const float*)d_in[18];
    const float* bo = (const float*)d_in[19];
    float* out = (float*)d_out;

    float* w = (float*)d_ws;
    // ---- zeroed region ----
    float* stats = w;                          // 384
    float* gsum = stats + 3 * 2 * H;           // 8192
    float* gcnt = gsum + N_GRAPHS * H;         // 128
    int* deg = (int*)(gcnt + N_GRAPHS);        // 50000
    const size_t zero_elems = 3 * 2 * H + N_GRAPHS * H + N_GRAPHS + N_NODES;
    // ---- scratch ----
    _Float16* ea_p = (_Float16*)(w + zero_elems);        // (800008)*48 f16 = 76.8 MB
    int* off = (int*)(ea_p + (size_t)(N_EDGES + 8) * KP);  // 50004
    int* cur = off + 50004;                              // 50000
    int* pos = cur + N_NODES;                            // 800000
    int* src_s = pos + N_EDGES;                          // 800000
    _Float16* W2pT = (_Float16*)(src_s + N_EDGES);       // 3*128*64 f16
    float* cfs = (float*)(W2pT + 3 * 128 * 64);          // 3*128
    float* state = cfs + 3 * 128;                        // 3.2M
    float* NPi = state + (size_t)N_NODES * H;            // 6.4M
    float* NPj = NPi + (size_t)N_NODES * 128;            // 6.4M
    // total ~148 MB (< 202.3 MB proven available in round 4/5)

    hipMemsetAsync(w, 0, zero_elems * sizeof(float), stream);

    fold_kernel<<<6, 256, 0, stream>>>(W_emb2, b_emb2, Wf, bf, Ws, bs, W2pT, cfs);
    embed_kernel<<<512, 256, 0, stream>>>(x, W_emb1, b_emb1, state);
    hist_kernel<<<(N_EDGES + 255) / 256, 256, 0, stream>>>(ei, deg);
    scan_kernel<<<1, 256, 0, stream>>>(deg, off, cur);
    scatter_kernel<<<(N_EDGES + 255) / 256, 256, 0, stream>>>(ei, cur, pos, src_s);
    pack_ea_kernel<<<4096, 256, 0, stream>>>(pos, ea, ea_p);

    for (int a = 0; a < N_CONV; ++a) {
        const float* sp = a > 0 ? stats + (a - 1) * 2 * H : stats;
        const float* gp = a > 0 ? gamma + (a - 1) * H : gamma;
        const float* bp = a > 0 ? beta + (a - 1) * H : beta;
        int mode = a > 0 ? 1 : 0;
        node_proj_bn_kernel<<<512, 256, 0, stream>>>(
            state, sp, gp, bp, Wf + a * 192 * H, Ws + a * 192 * H, NPi, NPj, mode);
        edge_mfma_kernel<<<2048, 256, 0, stream>>>(
            off, src_s, ea_p, NPi, NPj, W2pT + a * 128 * 64, cfs + a * 128,
            sp, gp, bp, state, stats + a * 2 * H, mode);
    }

    pool_bn_kernel<<<784, 256, 0, stream>>>(state, stats + 2 * 2 * H,
                                            gamma + 2 * H, beta + 2 * H,
                                            batch, gsum, gcnt);
    mlp_kernel<<<128, 64, 0, stream>>>(gsum, gcnt, W1, b1, W2, b2, Wo, bo, out);
}

// Round 9
// 1247.603 us; speedup vs baseline: 1.8289x; 1.2625x over previous
//
#include <hip/hip_runtime.h>
#include <hip/hip_bf16.h>
#include <hip/hip_fp16.h>
#include <math.h>

#define N_NODES 50000
#define N_EDGES 800000
#define N_GRAPHS 128
#define ORIG_FEA 92
#define NBR_FEA 41
#define H 64
#define N_CONV 3
#define BN_EPS 1e-5f
#define KP 48        // padded K per edge row (f16): 41 real + zeros

typedef _Float16 h8 __attribute__((ext_vector_type(8)));
typedef float f32x4 __attribute__((ext_vector_type(4)));

__device__ __forceinline__ float sigmoidf_(float x) {
    return __fdividef(1.f, 1.f + __expf(-x));
}
__device__ __forceinline__ float softplusf_(float x) {
    return fmaxf(x, 0.f) + __logf(1.f + __expf(-fabsf(x)));
}

// ---------------------------------------------------------------------------
// Fold W_emb2/b_emb2/biases. Output W2frag in per-lane MFMA B-fragment order:
//   frag = nt*2+ks (nt = gate*4 + (j>>4)), lane = g*16 + (j&15), elem i:
//   W2frag[((frag*64)+lane)*8 + i] = V(gate, j, k = ks*32+g*8+i)   (f16)
// cfs m15-grouped: cfs[(j&15)*8 + gate*4 + (j>>4)] = bias-fold(gate, j) (f32)
// ---------------------------------------------------------------------------
__global__ __launch_bounds__(256) void fold_kernel(
    const float* __restrict__ W_emb2, const float* __restrict__ b_emb2,
    const float* __restrict__ Wf, const float* __restrict__ bf,
    const float* __restrict__ Ws, const float* __restrict__ bs,
    _Float16* __restrict__ W2frag, float* __restrict__ cfs) {
    int a = blockIdx.x >> 1, gate = blockIdx.x & 1;
    const float* W = (gate ? Ws : Wf) + a * 192 * H + 128 * H;  // [64][64]
    const float* bias = (gate ? bs : bf) + a * H;
    _Float16* out = W2frag + a * 128 * 64;
    float* cout = cfs + a * 128;
    for (int idx = threadIdx.x; idx < 64 * 64; idx += blockDim.x) {
        int j = idx >> 6, k = idx & 63;
        float acc = 0.f;
        if (k < NBR_FEA)
            for (int m = 0; m < H; ++m) acc += W_emb2[k * H + m] * W[m * H + j];
        int frag = (gate * 4 + (j >> 4)) * 2 + (k >> 5);
        int lane = (((k & 31) >> 3) << 4) + (j & 15);
        out[(frag * 64 + lane) * 8 + (k & 7)] = (_Float16)acc;
    }
    for (int j = threadIdx.x; j < H; j += blockDim.x) {
        float acc = bias[j];
        for (int m = 0; m < H; ++m) acc += b_emb2[m] * W[m * H + j];
        cout[(j & 15) * 8 + gate * 4 + (j >> 4)] = acc;
    }
}

// ---------------------------------------------------------------------------
// h = x @ W_emb1 + b_emb1  -> state
// ---------------------------------------------------------------------------
__global__ __launch_bounds__(256) void embed_kernel(
    const float* __restrict__ x, const float* __restrict__ W,
    const float* __restrict__ b, float* __restrict__ state) {
    __shared__ float lw[ORIG_FEA * H];
    for (int i = threadIdx.x; i < ORIG_FEA * H; i += blockDim.x) lw[i] = W[i];
    __syncthreads();
    int lane = threadIdx.x & 63;
    int wid = (blockIdx.x * blockDim.x + threadIdx.x) >> 6;
    int nw = (gridDim.x * blockDim.x) >> 6;
    for (int n = wid; n < N_NODES; n += nw) {
        int nu = __builtin_amdgcn_readfirstlane(n);
        const float* xr = x + (size_t)nu * ORIG_FEA;
        float acc = b[lane];
#pragma unroll
        for (int k = 0; k < ORIG_FEA; ++k) acc += xr[k] * lw[k * H + lane];
        state[(size_t)nu * H + lane] = acc;
    }
}

// ---------------------------------------------------------------------------
// CSR construction
// ---------------------------------------------------------------------------
__global__ __launch_bounds__(256) void hist_kernel(
    const int* __restrict__ ei, int* __restrict__ deg) {
    int e = blockIdx.x * blockDim.x + threadIdx.x;
    if (e < N_EDGES) atomicAdd(&deg[ei[N_EDGES + e]], 1);
}

__global__ __launch_bounds__(256) void scan_kernel(
    const int* __restrict__ deg, int* __restrict__ off, int* __restrict__ cur) {
    __shared__ int part[256];
    const int CHN = (N_NODES + 255) / 256;
    int t = threadIdx.x;
    int lo = t * CHN, hi = min(lo + CHN, N_NODES);
    int s = 0;
    for (int i = lo; i < hi; ++i) s += deg[i];
    part[t] = s;
    __syncthreads();
    for (int o = 1; o < 256; o <<= 1) {
        int v = (t >= o) ? part[t - o] : 0;
        __syncthreads();
        part[t] += v;
        __syncthreads();
    }
    int run = (t == 0) ? 0 : part[t - 1];
    for (int i = lo; i < hi; ++i) {
        off[i] = run;
        cur[i] = run;
        run += deg[i];
    }
    if (t == 255) off[N_NODES] = run;
}

__global__ __launch_bounds__(256) void scatter_kernel(
    const int* __restrict__ ei, int* __restrict__ cur, int* __restrict__ pos,
    int* __restrict__ src_s) {
    int e = blockIdx.x * blockDim.x + threadIdx.x;
    if (e < N_EDGES) {
        int d = ei[N_EDGES + e];
        int p = atomicAdd(&cur[d], 1);
        pos[e] = p;
        src_s[p] = ei[e];
    }
}

// ---------------------------------------------------------------------------
// Pack edge_attr -> f16 rows [KP=48] in CSR slot order. Wave per edge:
// sequential coalesced read (168B), 96B packed write to CSR slot.
// ---------------------------------------------------------------------------
__global__ __launch_bounds__(256) void pack_ea_kernel(
    const int* __restrict__ pos, const float* __restrict__ ea,
    _Float16* __restrict__ ea_p) {
    int lane = threadIdx.x & 63;
    int wid = (blockIdx.x * blockDim.x + threadIdx.x) >> 6;
    int nw = (gridDim.x * blockDim.x) >> 6;
    for (int e = wid; e < N_EDGES; e += nw) {
        int eu = __builtin_amdgcn_readfirstlane(e);
        int p = __builtin_amdgcn_readfirstlane(pos[eu]);
        unsigned dw = 0;
        if (lane < 21) {
            const float* er = ea + (size_t)eu * NBR_FEA;
            float v0 = er[2 * lane];
            float v1 = (2 * lane + 1 < NBR_FEA) ? er[2 * lane + 1] : 0.f;
            union { _Float16 h[2]; unsigned u; } cv;
            cv.h[0] = (_Float16)v0;
            cv.h[1] = (_Float16)v1;
            dw = cv.u;
        }
        if (lane < KP / 2)
            *(unsigned*)(ea_p + (size_t)p * KP + 2 * lane) = dw;
    }
}

// ---------------------------------------------------------------------------
// node_proj_bn: (BN_{a-1}+ReLU if mode) fused with 4 projections.
// Outputs m15-grouped: NP[n][ (feat&15)*8 + (feat>>4) ]      = f-gate value
//                      NP[n][ (feat&15)*8 + 4 + (feat>>4) ]  = s-gate value
// ---------------------------------------------------------------------------
__global__ __launch_bounds__(256) void node_proj_bn_kernel(
    const float* __restrict__ state, const float* __restrict__ stats,
    const float* __restrict__ gamma, const float* __restrict__ beta,
    const float* __restrict__ Wf, const float* __restrict__ Ws,
    float* __restrict__ NPi, float* __restrict__ NPj, int mode) {
    __shared__ float lw[4 * H * H];
    __shared__ float slot[4][H];
    for (int i = threadIdx.x; i < H * H; i += blockDim.x) {
        lw[i] = Wf[i];
        lw[H * H + i] = Wf[H * H + i];
        lw[2 * H * H + i] = Ws[i];
        lw[3 * H * H + i] = Ws[H * H + i];
    }
    int lane = threadIdx.x & 63;
    int wl = threadIdx.x >> 6;
    int gbase = (lane & 15) * 8 + (lane >> 4);  // m15-grouped slot for feat=lane
    float A = 1.f, B = 0.f;
    if (mode) {
        const float inv_n = 1.f / (float)N_NODES;
        float mu = stats[lane] * inv_n;
        float var = stats[H + lane] * inv_n - mu * mu;
        float inv = rsqrtf(var + BN_EPS);
        A = inv * gamma[lane];
        B = beta[lane] - mu * A;
    }
    __syncthreads();
    int wid = (blockIdx.x * blockDim.x + threadIdx.x) >> 6;
    int nw = (gridDim.x * blockDim.x) >> 6;
    for (int n = wid; n < N_NODES; n += nw) {
        float z = state[(size_t)n * H + lane];
        float hn = mode ? fmaxf(z * A + B, 0.f) : z;
        slot[wl][lane] = hn;
        float pf = 0.f, qf = 0.f, ps = 0.f, qs = 0.f;
#pragma unroll
        for (int k = 0; k < H; ++k) {
            float s = slot[wl][k];
            pf += s * lw[k * H + lane];
            qf += s * lw[H * H + k * H + lane];
            ps += s * lw[2 * H * H + k * H + lane];
            qs += s * lw[3 * H * H + k * H + lane];
        }
        NPi[(size_t)n * 128 + gbase] = pf;
        NPi[(size_t)n * 128 + gbase + 4] = ps;
        NPj[(size_t)n * 128 + gbase] = qf;
        NPj[(size_t)n * 128 + gbase + 4] = qs;
    }
}

// ---------------------------------------------------------------------------
// Fused edge kernel: wave per node, CSR bucket in 16-edge MFMA tiles.
// B-frags loaded coalesced from fragment-major W2frag (no LDS, no sync).
// A-frags software-pipelined (next tile prefetched during epilogue).
// NPj gathers: 2 x dwordx4 per row (m15-grouped layout), 4 rows up front.
// ---------------------------------------------------------------------------
__global__ __launch_bounds__(256) void edge_mfma_kernel(
    const int* __restrict__ off, const int* __restrict__ src_s,
    const _Float16* __restrict__ ea_p,
    const float* __restrict__ NPi, const float* __restrict__ NPj,
    const _Float16* __restrict__ W2frag, const float* __restrict__ cfs,
    const float* __restrict__ stats_prev, const float* __restrict__ gamma,
    const float* __restrict__ beta, float* __restrict__ state,
    float* __restrict__ stats_out, int mode) {
    int lane = threadIdx.x & 63;
    int m15 = lane & 15, g = lane >> 4;
    // B fragments: 16 coalesced dwordx4 from fragment-major array
    h8 bfr[8][2];
#pragma unroll
    for (int nt = 0; nt < 8; ++nt)
#pragma unroll
        for (int ks = 0; ks < 2; ++ks) {
            union { uint4 u; h8 h; } cv;
            cv.u = *(const uint4*)(W2frag + (size_t)(((nt * 2 + ks) * 64) + lane) * 8);
            bfr[nt][ks] = cv.h;
        }
    f32x4 cflo = *(const f32x4*)(cfs + m15 * 8);
    f32x4 cfhi = *(const f32x4*)(cfs + m15 * 8 + 4);
    float A = 1.f, B = 0.f;
    if (mode) {
        const float inv_n = 1.f / (float)N_NODES;
        float mu = stats_prev[lane] * inv_n;
        float var = stats_prev[H + lane] * inv_n - mu * mu;
        float inv = rsqrtf(var + BN_EPS);
        A = inv * gamma[lane];
        B = beta[lane] - mu * A;
    }
    float s = 0.f, s2 = 0.f;
    int wid = (blockIdx.x * blockDim.x + threadIdx.x) >> 6;
    int nw = (gridDim.x * blockDim.x) >> 6;
    for (int n = wid; n < N_NODES; n += nw) {
        int nu = __builtin_amdgcn_readfirstlane(n);
        float z = state[(size_t)nu * H + lane];
        float acc = mode ? fmaxf(z * A + B, 0.f) : z;  // residual h
        // per-node bias terms (m15-grouped: 2 x dwordx4)
        f32x4 nplo = *(const f32x4*)(NPi + (size_t)nu * 128 + m15 * 8);
        f32x4 nphi = *(const f32x4*)(NPi + (size_t)nu * 128 + m15 * 8 + 4);
        f32x4 bfv = cflo + nplo;
        f32x4 bsv = cfhi + nphi;
        int e0 = __builtin_amdgcn_readfirstlane(off[nu]);
        int e1 = __builtin_amdgcn_readfirstlane(off[nu + 1]);
        if (e0 >= e1) {
            state[(size_t)nu * H + lane] = acc;
            s += acc;
            s2 += acc * acc;
            continue;
        }
        // prologue A-frag load for tile 0
        h8 afr0, afr1;
        {
            int arow = min(e0 + m15, e1 - 1);
            const _Float16* rowp = ea_p + (size_t)arow * KP;
            union { uint4 u; h8 h; } cv0, cv1;
            cv0.u = *(const uint4*)(rowp + g * 8);
            afr0 = cv0.h;
            const _Float16* p1 = rowp + ((g < 2) ? (32 + g * 8) : 0);
            uint4 r1 = *(const uint4*)p1;
            if (g >= 2) { r1.x = 0u; r1.y = 0u; r1.z = 0u; r1.w = 0u; }
            cv1.u = r1;
            afr1 = cv1.h;
        }
        for (int e = e0; e < e1; e += 16) {
            int cnt = e1 - e;
            f32x4 c[8];
#pragma unroll
            for (int nt = 0; nt < 8; ++nt) c[nt] = (f32x4)(0.f);
#pragma unroll
            for (int nt = 0; nt < 8; ++nt)
                c[nt] = __builtin_amdgcn_mfma_f32_16x16x32_f16(afr0, bfr[nt][0],
                                                               c[nt], 0, 0, 0);
#pragma unroll
            for (int nt = 0; nt < 8; ++nt)
                c[nt] = __builtin_amdgcn_mfma_f32_16x16x32_f16(afr1, bfr[nt][1],
                                                               c[nt], 0, 0, 0);
            // prefetch next tile's A-frags (hidden under epilogue)
            int en = e + 16;
            if (en < e1) {
                int arow = min(en + m15, e1 - 1);
                const _Float16* rowp = ea_p + (size_t)arow * KP;
                union { uint4 u; h8 h; } cv0, cv1;
                cv0.u = *(const uint4*)(rowp + g * 8);
                afr0 = cv0.h;
                const _Float16* p1 = rowp + ((g < 2) ? (32 + g * 8) : 0);
                uint4 r1 = *(const uint4*)p1;
                if (g >= 2) { r1.x = 0u; r1.y = 0u; r1.z = 0u; r1.w = 0u; }
                cv1.u = r1;
                afr1 = cv1.h;
            }
            // gather NPj rows (4 rows x 2 dwordx4, independent chains)
            f32x4 ql[4], qh[4];
            float mul[4];
#pragma unroll
            for (int r = 0; r < 4; ++r) {
                int rr = 4 * g + r;
                int ee = e + ((rr < cnt) ? rr : (cnt - 1));
                int sv = src_s[ee];
                const float* qp = NPj + (size_t)sv * 128 + m15 * 8;
                ql[r] = *(const f32x4*)qp;
                qh[r] = *(const f32x4*)(qp + 4);
                mul[r] = (rr < cnt) ? 1.f : 0.f;
            }
            float ts0 = 0.f, ts1 = 0.f, ts2 = 0.f, ts3 = 0.f;
#pragma unroll
            for (int r = 0; r < 4; ++r) {
                {
                    float af = c[0][r] + bfv[0] + ql[r][0];
                    float as = c[4][r] + bsv[0] + qh[r][0];
                    ts0 += mul[r] * sigmoidf_(af) * softplusf_(as);
                }
                {
                    float af = c[1][r] + bfv[1] + ql[r][1];
                    float as = c[5][r] + bsv[1] + qh[r][1];
                    ts1 += mul[r] * sigmoidf_(af) * softplusf_(as);
                }
                {
                    float af = c[2][r] + bfv[2] + ql[r][2];
                    float as = c[6][r] + bsv[2] + qh[r][2];
                    ts2 += mul[r] * sigmoidf_(af) * softplusf_(as);
                }
                {
                    float af = c[3][r] + bfv[3] + ql[r][3];
                    float as = c[7][r] + bsv[3] + qh[r][3];
                    ts3 += mul[r] * sigmoidf_(af) * softplusf_(as);
                }
            }
            ts0 += __shfl_xor(ts0, 16, 64); ts0 += __shfl_xor(ts0, 32, 64);
            ts1 += __shfl_xor(ts1, 16, 64); ts1 += __shfl_xor(ts1, 32, 64);
            ts2 += __shfl_xor(ts2, 16, 64); ts2 += __shfl_xor(ts2, 32, 64);
            ts3 += __shfl_xor(ts3, 16, 64); ts3 += __shfl_xor(ts3, 32, 64);
            float v = (g & 2) ? ((g & 1) ? ts3 : ts2) : ((g & 1) ? ts1 : ts0);
            acc += v;
        }
        state[(size_t)nu * H + lane] = acc;
        s += acc;
        s2 += acc * acc;
    }
    atomicAdd(&stats_out[lane], s);
    atomicAdd(&stats_out[H + lane], s2);
}

// ---------------------------------------------------------------------------
// Pool with fused final BN. batch is SORTED: contiguous node range per wave,
// local accumulate, one atomic row per graph transition.
// ---------------------------------------------------------------------------
__global__ __launch_bounds__(256) void pool_bn_kernel(
    const float* __restrict__ state, const float* __restrict__ stats,
    const float* __restrict__ gamma, const float* __restrict__ beta,
    const int* __restrict__ batch, float* __restrict__ gsum,
    float* __restrict__ gcnt) {
    int lane = threadIdx.x & 63;
    const float inv_n = 1.f / (float)N_NODES;
    float mu = stats[lane] * inv_n;
    float var = stats[H + lane] * inv_n - mu * mu;
    float inv = rsqrtf(var + BN_EPS);
    float A = inv * gamma[lane];
    float B = beta[lane] - mu * A;
    int wid = (blockIdx.x * blockDim.x + threadIdx.x) >> 6;
    int nw = (gridDim.x * blockDim.x) >> 6;
    int per = (N_NODES + nw - 1) / nw;
    int lo = wid * per, hi = min(lo + per, N_NODES);
    if (lo >= hi) return;
    int gcur = __builtin_amdgcn_readfirstlane(batch[lo]);
    float accv = 0.f, cntv = 0.f;
    for (int n = lo; n < hi; ++n) {
        int gn = __builtin_amdgcn_readfirstlane(batch[n]);
        if (gn != gcur) {
            atomicAdd(&gsum[(size_t)gcur * H + lane], accv);
            if (lane == 0) atomicAdd(&gcnt[gcur], cntv);
            gcur = gn;
            accv = 0.f;
            cntv = 0.f;
        }
        accv += state[(size_t)n * H + lane] * A + B;
        cntv += 1.f;
    }
    atomicAdd(&gsum[(size_t)gcur * H + lane], accv);
    if (lane == 0) atomicAdd(&gcnt[gcur], cntv);
}

__global__ __launch_bounds__(64) void mlp_kernel(
    const float* __restrict__ gsum, const float* __restrict__ gcnt,
    const float* __restrict__ W1, const float* __restrict__ b1,
    const float* __restrict__ W2, const float* __restrict__ b2,
    const float* __restrict__ Wo, const float* __restrict__ bo,
    float* __restrict__ out) {
    int g = blockIdx.x;
    int lane = threadIdx.x;
    __shared__ float y[H];
    float cnt = fmaxf(gcnt[g], 1.f);
    y[lane] = gsum[(size_t)g * H + lane] / cnt;
    __syncthreads();
    float acc = b1[lane];
#pragma unroll
    for (int k = 0; k < H; ++k) acc += y[k] * W1[k * H + lane];
    float y1 = softplusf_(acc);
    __syncthreads();
    y[lane] = y1;
    __syncthreads();
    acc = b2[lane];
#pragma unroll
    for (int k = 0; k < H; ++k) acc += y[k] * W2[k * H + lane];
    float y2 = softplusf_(acc);
    float t = y2 * Wo[lane];
#pragma unroll
    for (int o = 32; o > 0; o >>= 1) t += __shfl_down(t, o, 64);
    if (lane == 0) out[g] = t + bo[0];
}

extern "C" void kernel_launch(void* const* d_in, const int* in_sizes, int n_in,
                              void* d_out, int out_size, void* d_ws, size_t ws_size,
                              hipStream_t stream) {
    const float* x = (const float*)d_in[0];
    const float* ea = (const float*)d_in[1];
    const int* ei = (const int*)d_in[2];
    const int* batch = (const int*)d_in[3];
    const float* W_emb1 = (const float*)d_in[4];
    const float* b_emb1 = (const float*)d_in[5];
    const float* W_emb2 = (const float*)d_in[6];
    const float* b_emb2 = (const float*)d_in[7];
    const float* Wf = (const float*)d_in[8];
    const float* bf = (const float*)d_in[9];
    const float* Ws = (const float*)d_in[10];
    const float* bs = (const float*)d_in[11];
    const float* gamma = (const float*)d_in[12];
    const float* beta = (const float*)d_in[13];
    const float* W1 = (const float*)d_in[14];
    const float* b1 = (const float*)d_in[15];
    const float* W2 = (const float*)d_in[16];
    const float* b2 = (const float*)d_in[17];
    const float* Wo = (const float*)d_in[18];
    const float* bo = (const float*)d_in[19];
    float* out = (float*)d_out;

    float* w = (float*)d_ws;
    // ---- zeroed region ----
    float* stats = w;                          // 384
    float* gsum = stats + 3 * 2 * H;           // 8192
    float* gcnt = gsum + N_GRAPHS * H;         // 128
    int* deg = (int*)(gcnt + N_GRAPHS);        // 50000
    const size_t zero_elems = 3 * 2 * H + N_GRAPHS * H + N_GRAPHS + N_NODES;
    // ---- scratch ----
    _Float16* ea_p = (_Float16*)(w + zero_elems);        // (800008)*48 f16
    int* off = (int*)(ea_p + (size_t)(N_EDGES + 8) * KP);  // 50004
    int* cur = off + 50004;                              // 50000
    int* pos = cur + N_NODES;                            // 800000
    int* src_s = pos + N_EDGES;                          // 800000
    _Float16* W2frag = (_Float16*)(src_s + N_EDGES);     // 3*128*64 f16
    float* cfs = (float*)(W2frag + 3 * 128 * 64);        // 3*128
    float* state = cfs + 3 * 128;                        // 3.2M
    float* NPi = state + (size_t)N_NODES * H;            // 6.4M
    float* NPj = NPi + (size_t)N_NODES * 128;            // 6.4M
    // total ~148 MB

    hipMemsetAsync(w, 0, zero_elems * sizeof(float), stream);

    fold_kernel<<<6, 256, 0, stream>>>(W_emb2, b_emb2, Wf, bf, Ws, bs, W2frag, cfs);
    embed_kernel<<<512, 256, 0, stream>>>(x, W_emb1, b_emb1, state);
    hist_kernel<<<(N_EDGES + 255) / 256, 256, 0, stream>>>(ei, deg);
    scan_kernel<<<1, 256, 0, stream>>>(deg, off, cur);
    scatter_kernel<<<(N_EDGES + 255) / 256, 256, 0, stream>>>(ei, cur, pos, src_s);
    pack_ea_kernel<<<2048, 256, 0, stream>>>(pos, ea, ea_p);

    for (int a = 0; a < N_CONV; ++a) {
        const float* sp = a > 0 ? stats + (a - 1) * 2 * H : stats;
        const float* gp = a > 0 ? gamma + (a - 1) * H : gamma;
        const float* bp = a > 0 ? beta + (a - 1) * H : beta;
        int mode = a > 0 ? 1 : 0;
        node_proj_bn_kernel<<<512, 256, 0, stream>>>(
            state, sp, gp, bp, Wf + a * 192 * H, Ws + a * 192 * H, NPi, NPj, mode);
        edge_mfma_kernel<<<2048, 256, 0, stream>>>(
            off, src_s, ea_p, NPi, NPj, W2frag + a * 128 * 64, cfs + a * 128,
            sp, gp, bp, state, stats + a * 2 * H, mode);
    }

    pool_bn_kernel<<<784, 256, 0, stream>>>(state, stats + 2 * 2 * H,
                                            gamma + 2 * H, beta + 2 * H,
                                            batch, gsum, gcnt);
    mlp_kernel<<<128, 64, 0, stream>>>(gsum, gcnt, W1, b1, W2, b2, Wo, bo, out);
}